// Round 12
// baseline (32.845 us; speedup 1.0000x reference)
//
#include <hip/hip_runtime.h>
#include <hip/hip_bf16.h>

typedef __attribute__((ext_vector_type(4))) float f32x4;
typedef __attribute__((ext_vector_type(8))) short s16x8;
typedef __attribute__((ext_vector_type(2))) __fp16 h16x2;

// inputs: [3136][64][16] f32, W: [10][64][16][16] f32, out: [3136][10][16] f32.
// Gram-space routing per (pos,n): G = R^T R (MFMA bf16), s0 = (1/64) R^T 1,
// s += G*squash(s) x2, out = squash(s).
//
// R12 = R11's verified einsum/phase-B subsystems, restructured one-shot:
// block = (n, 16 positions); einsum all 16 -> ONE barrier -> each wave runs
// FOUR independent routing chains interleaved (latency amortized 4x);
// launch_bounds(256,4) for 4 resident blocks/CU.

template<int CTRL>
__device__ __forceinline__ float dpp_add(float x) {
    int v = __builtin_amdgcn_update_dpp(0, __float_as_int(x), CTRL, 0xF, 0xF, true);
    return x + __int_as_float(v);
}
template<int CTRL>
__device__ __forceinline__ int dpp_mov(int x) {
    return __builtin_amdgcn_update_dpp(0, x, CTRL, 0xF, 0xF, true);
}
__device__ __forceinline__ h16x2 bch(int x) { return __builtin_bit_cast(h16x2, x); }
__device__ __forceinline__ int bci(h16x2 x) { return __builtin_bit_cast(int, x); }

__global__ __launch_bounds__(256, 4) void caps_kernel(
    const float* __restrict__ inp,
    const float* __restrict__ W,
    float* __restrict__ out)
{
    const int tid = threadIdx.x;
    const int w   = tid >> 6;
    const int l   = tid & 63;
    const int n   = blockIdx.x / 196;
    const int pg  = blockIdx.x % 196;
    const int pos0 = pg * 16;

    extern __shared__ __align__(16) char smem[];
    char* rbuf = smem;                 // res single buffer: 16 pos x 2KB = 32KB

    const int i4 = l >> 2;          // row within 16-block
    const int oq = l & 3;           // o-quad / own e-chunk
    const int i_ = w * 16 + i4;     // input capsule 0..63
    const int col = l & 15;
    const int kg  = l >> 4;

    // ---- W straight to regs, rotation-ordered, packed f16 pairs (R11-verified)
    const float* wb = W + (size_t)n * 16384 + i_ * 256 + oq * 4;
    h16x2 wpk[32];
#pragma unroll
    for (int r = 0; r < 4; ++r) {
        int c = (oq + r) & 3;
        f32x4 w0 = *(const f32x4*)(wb + (c * 4 + 0) * 16);
        f32x4 w1 = *(const f32x4*)(wb + (c * 4 + 1) * 16);
        f32x4 w2 = *(const f32x4*)(wb + (c * 4 + 2) * 16);
        f32x4 w3 = *(const f32x4*)(wb + (c * 4 + 3) * 16);
#pragma unroll
        for (int dd = 0; dd < 4; ++dd) {
            wpk[r * 8 + dd]     = __builtin_amdgcn_cvt_pkrtz(w0[dd], w1[dd]);
            wpk[r * 8 + 4 + dd] = __builtin_amdgcn_cvt_pkrtz(w2[dd], w3[dd]);
        }
    }

    // ---- all 16 positions' inp loads issued up front (coalesced 16B/lane)
    f32x4 raw[16];
#pragma unroll
    for (int pp = 0; pp < 16; ++pp)
        raw[pp] = *(const f32x4*)(inp + (size_t)(pos0 + pp) * 1024 + w * 256 + l * 4);

    s16x8 ones;
#pragma unroll
    for (int j = 0; j < 8; ++j) ones[j] = (short)0x3F80;  // bf16 1.0

    // ---- einsum (R11-verified fdot2): res[pp][i_][oq*4+dd] = sum_e inp*W
#pragma unroll
    for (int pp = 0; pp < 16; ++pp) {
        f32x4 a = raw[pp];
        int iA = bci(__builtin_amdgcn_cvt_pkrtz(a[0], a[1]));
        int iB = bci(__builtin_amdgcn_cvt_pkrtz(a[2], a[3]));
        float acc0 = 0.f, acc1 = 0.f, acc2 = 0.f, acc3 = 0.f;

        acc0 = __builtin_amdgcn_fdot2(bch(iA), wpk[0], acc0, false);
        acc1 = __builtin_amdgcn_fdot2(bch(iA), wpk[1], acc1, false);
        acc2 = __builtin_amdgcn_fdot2(bch(iA), wpk[2], acc2, false);
        acc3 = __builtin_amdgcn_fdot2(bch(iA), wpk[3], acc3, false);
        acc0 = __builtin_amdgcn_fdot2(bch(iB), wpk[4], acc0, false);
        acc1 = __builtin_amdgcn_fdot2(bch(iB), wpk[5], acc1, false);
        acc2 = __builtin_amdgcn_fdot2(bch(iB), wpk[6], acc2, false);
        acc3 = __builtin_amdgcn_fdot2(bch(iB), wpk[7], acc3, false);
        {
            int jA = dpp_mov<0x39>(iA), jB = dpp_mov<0x39>(iB);
            acc0 = __builtin_amdgcn_fdot2(bch(jA), wpk[8],  acc0, false);
            acc1 = __builtin_amdgcn_fdot2(bch(jA), wpk[9],  acc1, false);
            acc2 = __builtin_amdgcn_fdot2(bch(jA), wpk[10], acc2, false);
            acc3 = __builtin_amdgcn_fdot2(bch(jA), wpk[11], acc3, false);
            acc0 = __builtin_amdgcn_fdot2(bch(jB), wpk[12], acc0, false);
            acc1 = __builtin_amdgcn_fdot2(bch(jB), wpk[13], acc1, false);
            acc2 = __builtin_amdgcn_fdot2(bch(jB), wpk[14], acc2, false);
            acc3 = __builtin_amdgcn_fdot2(bch(jB), wpk[15], acc3, false);
        }
        {
            int jA = dpp_mov<0x4E>(iA), jB = dpp_mov<0x4E>(iB);
            acc0 = __builtin_amdgcn_fdot2(bch(jA), wpk[16], acc0, false);
            acc1 = __builtin_amdgcn_fdot2(bch(jA), wpk[17], acc1, false);
            acc2 = __builtin_amdgcn_fdot2(bch(jA), wpk[18], acc2, false);
            acc3 = __builtin_amdgcn_fdot2(bch(jA), wpk[19], acc3, false);
            acc0 = __builtin_amdgcn_fdot2(bch(jB), wpk[20], acc0, false);
            acc1 = __builtin_amdgcn_fdot2(bch(jB), wpk[21], acc1, false);
            acc2 = __builtin_amdgcn_fdot2(bch(jB), wpk[22], acc2, false);
            acc3 = __builtin_amdgcn_fdot2(bch(jB), wpk[23], acc3, false);
        }
        {
            int jA = dpp_mov<0x93>(iA), jB = dpp_mov<0x93>(iB);
            acc0 = __builtin_amdgcn_fdot2(bch(jA), wpk[24], acc0, false);
            acc1 = __builtin_amdgcn_fdot2(bch(jA), wpk[25], acc1, false);
            acc2 = __builtin_amdgcn_fdot2(bch(jA), wpk[26], acc2, false);
            acc3 = __builtin_amdgcn_fdot2(bch(jA), wpk[27], acc3, false);
            acc0 = __builtin_amdgcn_fdot2(bch(jB), wpk[28], acc0, false);
            acc1 = __builtin_amdgcn_fdot2(bch(jB), wpk[29], acc1, false);
            acc2 = __builtin_amdgcn_fdot2(bch(jB), wpk[30], acc2, false);
            acc3 = __builtin_amdgcn_fdot2(bch(jB), wpk[31], acc3, false);
        }

        // bf16 scatter into [pp][o][i] (chunk-XOR swizzle) — verified
        float accv[4] = {acc0, acc1, acc2, acc3};
#pragma unroll
        for (int dd = 0; dd < 4; ++dd) {
            int o = oq * 4 + dd;
            __hip_bfloat16 bb = __float2bfloat16(accv[dd]);
            int byte = pp * 2048 + o * 128 + (((i_ >> 3) ^ (o & 7)) << 4) + (i_ & 7) * 2;
            *(unsigned short*)(rbuf + byte) = *(unsigned short*)&bb;
        }
    }

    // ---- ONE barrier for the whole block
    asm volatile("s_waitcnt lgkmcnt(0)" ::: "memory");
    __builtin_amdgcn_s_barrier();
    asm volatile("" ::: "memory");
    __builtin_amdgcn_sched_barrier(0);

    // ---- phase B: wave w runs 4 independent chains: pp = c*4 + w
    float s[4];
    f32x4 G[4];
#pragma unroll
    for (int c = 0; c < 4; ++c) {
        const int pp = c * 4 + w;
        s16x8 fr0 = *(const s16x8*)(rbuf + pp * 2048 + col * 128 + (((kg + 0) ^ (col & 7)) << 4));
        s16x8 fr1 = *(const s16x8*)(rbuf + pp * 2048 + col * 128 + (((kg + 4) ^ (col & 7)) << 4));
        f32x4 g  = (f32x4)0.0f;
        f32x4 c2 = (f32x4)0.0f;
        g  = __builtin_amdgcn_mfma_f32_16x16x32_bf16(fr0, fr0, g, 0, 0, 0);
        g  = __builtin_amdgcn_mfma_f32_16x16x32_bf16(fr1, fr1, g, 0, 0, 0);
        c2 = __builtin_amdgcn_mfma_f32_16x16x32_bf16(ones, fr0, c2, 0, 0, 0);
        c2 = __builtin_amdgcn_mfma_f32_16x16x32_bf16(ones, fr1, c2, 0, 0, 0);
        G[c] = g;
        s[c] = c2[0] * (1.0f / 64.0f);
    }

#pragma unroll
    for (int it = 0; it < 2; ++it) {
#pragma unroll
        for (int c = 0; c < 4; ++c) {
            float sn = s[c] * s[c];
            sn = dpp_add<0xB1>(sn);
            sn = dpp_add<0x4E>(sn);
            sn = dpp_add<0x124>(sn);
            sn = dpp_add<0x128>(sn);
            float scale = sqrtf(sn) / (1.0f + sn);
            float v = scale * s[c];
            float v0 = __shfl(v, kg * 4 + 0);
            float v1 = __shfl(v, kg * 4 + 1);
            float v2 = __shfl(v, kg * 4 + 2);
            float v3 = __shfl(v, kg * 4 + 3);
            float acc = G[c][0] * v0 + G[c][1] * v1 + G[c][2] * v2 + G[c][3] * v3;
            acc += __shfl_xor(acc, 16);
            acc += __shfl_xor(acc, 32);
            s[c] += acc;
        }
    }

#pragma unroll
    for (int c = 0; c < 4; ++c) {
        float sn = s[c] * s[c];
        sn = dpp_add<0xB1>(sn);
        sn = dpp_add<0x4E>(sn);
        sn = dpp_add<0x124>(sn);
        sn = dpp_add<0x128>(sn);
        float scale = sqrtf(sn) / (1.0f + sn);
        float v = scale * s[c];
        if (l < 16)
            out[((size_t)(pos0 + c * 4 + w) * 10 + n) * 16 + col] = v;
    }
}

extern "C" void kernel_launch(void* const* d_in, const int* in_sizes, int n_in,
                              void* d_out, int out_size, void* d_ws, size_t ws_size,
                              hipStream_t stream) {
    const float* inp = (const float*)d_in[0];   // [3136][64][16]
    const float* W   = (const float*)d_in[1];   // [10][64][16][16]
    float* out = (float*)d_out;                 // [3136][10][16]

    // 10 n * 196 groups of 16 positions (196*16 = 3136); 32 KB dyn LDS
    dim3 grid(1960), block(256);
    hipLaunchKernelGGL(caps_kernel, grid, block, 32768, stream, inp, W, out);
}

// Round 13
// 32.560 us; speedup vs baseline: 1.0088x; 1.0088x over previous
//
#include <hip/hip_runtime.h>
#include <hip/hip_bf16.h>

typedef __attribute__((ext_vector_type(4))) float f32x4;
typedef __attribute__((ext_vector_type(8))) short s16x8;
typedef __attribute__((ext_vector_type(2))) __fp16 h16x2;

// inputs: [3136][64][16] f32, W: [10][64][16][16] f32, out: [3136][10][16] f32.
// Gram-space routing per (pos,n): G = R^T R (MFMA bf16), s0 = (1/64) R^T 1,
// s += G*squash(s) x2, out = squash(s).
//
// R13 = one-shot block (16 positions, ONE barrier, 4 routing chains/wave)
// with clean VGPR budget (einsum in two 8-position batches, raw[8] only),
// and routing gather cost halved: 1 ds_bpermute + 4 DPP quad-broadcasts
// replaces 4 __shfl. launch_bounds(256,4); 32KB LDS; grid 1960.

template<int CTRL>
__device__ __forceinline__ float dpp_add(float x) {
    int v = __builtin_amdgcn_update_dpp(0, __float_as_int(x), CTRL, 0xF, 0xF, true);
    return x + __int_as_float(v);
}
template<int CTRL>
__device__ __forceinline__ int dpp_mov(int x) {
    return __builtin_amdgcn_update_dpp(0, x, CTRL, 0xF, 0xF, true);
}
__device__ __forceinline__ h16x2 bch(int x) { return __builtin_bit_cast(h16x2, x); }
__device__ __forceinline__ int bci(h16x2 x) { return __builtin_bit_cast(int, x); }

// einsum for one position: 32 fdot2 against wpk[], then bf16 scatter.
#define EINSUM_PP(ARAW, PP)                                                     \
    {                                                                           \
        f32x4 a = (ARAW);                                                       \
        int iA = bci(__builtin_amdgcn_cvt_pkrtz(a[0], a[1]));                   \
        int iB = bci(__builtin_amdgcn_cvt_pkrtz(a[2], a[3]));                   \
        float acc0 = 0.f, acc1 = 0.f, acc2 = 0.f, acc3 = 0.f;                   \
        acc0 = __builtin_amdgcn_fdot2(bch(iA), wpk[0], acc0, false);            \
        acc1 = __builtin_amdgcn_fdot2(bch(iA), wpk[1], acc1, false);            \
        acc2 = __builtin_amdgcn_fdot2(bch(iA), wpk[2], acc2, false);            \
        acc3 = __builtin_amdgcn_fdot2(bch(iA), wpk[3], acc3, false);            \
        acc0 = __builtin_amdgcn_fdot2(bch(iB), wpk[4], acc0, false);            \
        acc1 = __builtin_amdgcn_fdot2(bch(iB), wpk[5], acc1, false);            \
        acc2 = __builtin_amdgcn_fdot2(bch(iB), wpk[6], acc2, false);            \
        acc3 = __builtin_amdgcn_fdot2(bch(iB), wpk[7], acc3, false);            \
        {                                                                       \
            int jA = dpp_mov<0x39>(iA), jB = dpp_mov<0x39>(iB);                 \
            acc0 = __builtin_amdgcn_fdot2(bch(jA), wpk[8],  acc0, false);       \
            acc1 = __builtin_amdgcn_fdot2(bch(jA), wpk[9],  acc1, false);       \
            acc2 = __builtin_amdgcn_fdot2(bch(jA), wpk[10], acc2, false);       \
            acc3 = __builtin_amdgcn_fdot2(bch(jA), wpk[11], acc3, false);       \
            acc0 = __builtin_amdgcn_fdot2(bch(jB), wpk[12], acc0, false);       \
            acc1 = __builtin_amdgcn_fdot2(bch(jB), wpk[13], acc1, false);       \
            acc2 = __builtin_amdgcn_fdot2(bch(jB), wpk[14], acc2, false);       \
            acc3 = __builtin_amdgcn_fdot2(bch(jB), wpk[15], acc3, false);       \
        }                                                                       \
        {                                                                       \
            int jA = dpp_mov<0x4E>(iA), jB = dpp_mov<0x4E>(iB);                 \
            acc0 = __builtin_amdgcn_fdot2(bch(jA), wpk[16], acc0, false);       \
            acc1 = __builtin_amdgcn_fdot2(bch(jA), wpk[17], acc1, false);       \
            acc2 = __builtin_amdgcn_fdot2(bch(jA), wpk[18], acc2, false);       \
            acc3 = __builtin_amdgcn_fdot2(bch(jA), wpk[19], acc3, false);       \
            acc0 = __builtin_amdgcn_fdot2(bch(jB), wpk[20], acc0, false);       \
            acc1 = __builtin_amdgcn_fdot2(bch(jB), wpk[21], acc1, false);       \
            acc2 = __builtin_amdgcn_fdot2(bch(jB), wpk[22], acc2, false);       \
            acc3 = __builtin_amdgcn_fdot2(bch(jB), wpk[23], acc3, false);       \
        }                                                                       \
        {                                                                       \
            int jA = dpp_mov<0x93>(iA), jB = dpp_mov<0x93>(iB);                 \
            acc0 = __builtin_amdgcn_fdot2(bch(jA), wpk[24], acc0, false);       \
            acc1 = __builtin_amdgcn_fdot2(bch(jA), wpk[25], acc1, false);       \
            acc2 = __builtin_amdgcn_fdot2(bch(jA), wpk[26], acc2, false);       \
            acc3 = __builtin_amdgcn_fdot2(bch(jA), wpk[27], acc3, false);       \
            acc0 = __builtin_amdgcn_fdot2(bch(jB), wpk[28], acc0, false);       \
            acc1 = __builtin_amdgcn_fdot2(bch(jB), wpk[29], acc1, false);       \
            acc2 = __builtin_amdgcn_fdot2(bch(jB), wpk[30], acc2, false);       \
            acc3 = __builtin_amdgcn_fdot2(bch(jB), wpk[31], acc3, false);       \
        }                                                                       \
        float accv[4] = {acc0, acc1, acc2, acc3};                               \
        _Pragma("unroll")                                                       \
        for (int dd = 0; dd < 4; ++dd) {                                        \
            int o = oq * 4 + dd;                                                \
            __hip_bfloat16 bb = __float2bfloat16(accv[dd]);                     \
            int byte = (PP) * 2048 + o * 128 +                                  \
                       (((i_ >> 3) ^ (o & 7)) << 4) + (i_ & 7) * 2;             \
            *(unsigned short*)(rbuf + byte) = *(unsigned short*)&bb;            \
        }                                                                       \
    }

__global__ __launch_bounds__(256, 4) void caps_kernel(
    const float* __restrict__ inp,
    const float* __restrict__ W,
    float* __restrict__ out)
{
    const int tid = threadIdx.x;
    const int w   = tid >> 6;
    const int l   = tid & 63;
    const int n   = blockIdx.x / 196;
    const int pg  = blockIdx.x % 196;
    const int pos0 = pg * 16;

    extern __shared__ __align__(16) char smem[];
    char* rbuf = smem;                 // res single buffer: 16 pos x 2KB = 32KB

    const int i4 = l >> 2;          // row within 16-block
    const int oq = l & 3;           // o-quad / own e-chunk
    const int i_ = w * 16 + i4;     // input capsule 0..63
    const int col = l & 15;
    const int kg  = l >> 4;

    // ---- W straight to regs, rotation-ordered, packed f16 pairs (verified)
    const float* wb = W + (size_t)n * 16384 + i_ * 256 + oq * 4;
    h16x2 wpk[32];
#pragma unroll
    for (int r = 0; r < 4; ++r) {
        int c = (oq + r) & 3;
        f32x4 w0 = *(const f32x4*)(wb + (c * 4 + 0) * 16);
        f32x4 w1 = *(const f32x4*)(wb + (c * 4 + 1) * 16);
        f32x4 w2 = *(const f32x4*)(wb + (c * 4 + 2) * 16);
        f32x4 w3 = *(const f32x4*)(wb + (c * 4 + 3) * 16);
#pragma unroll
        for (int dd = 0; dd < 4; ++dd) {
            wpk[r * 8 + dd]     = __builtin_amdgcn_cvt_pkrtz(w0[dd], w1[dd]);
            wpk[r * 8 + 4 + dd] = __builtin_amdgcn_cvt_pkrtz(w2[dd], w3[dd]);
        }
    }

    s16x8 ones;
#pragma unroll
    for (int j = 0; j < 8; ++j) ones[j] = (short)0x3F80;  // bf16 1.0

    // ---- einsum in two 8-position batches (raw[8] keeps VGPR <=128)
    {
        f32x4 raw[8];
#pragma unroll
        for (int j = 0; j < 8; ++j)
            raw[j] = *(const f32x4*)(inp + (size_t)(pos0 + j) * 1024 + w * 256 + l * 4);
#pragma unroll
        for (int j = 0; j < 8; ++j)
            EINSUM_PP(raw[j], j)
#pragma unroll
        for (int j = 0; j < 8; ++j)
            raw[j] = *(const f32x4*)(inp + (size_t)(pos0 + 8 + j) * 1024 + w * 256 + l * 4);
#pragma unroll
        for (int j = 0; j < 8; ++j)
            EINSUM_PP(raw[j], 8 + j)
    }

    // ---- ONE barrier for the whole block
    asm volatile("s_waitcnt lgkmcnt(0)" ::: "memory");
    __builtin_amdgcn_s_barrier();
    asm volatile("" ::: "memory");
    __builtin_amdgcn_sched_barrier(0);

    // ---- phase B: wave w runs 4 independent chains: pp = c*4 + w
    // gather byte-index for bpermute: pull v[kg*4 + (l&3)] from own 16-group
    const int pidx = (((l & 48) | (((l & 48) >> 2) + (l & 3))) << 2);

    float s[4];
    f32x4 G[4];
#pragma unroll
    for (int c = 0; c < 4; ++c) {
        const int pp = c * 4 + w;
        s16x8 fr0 = *(const s16x8*)(rbuf + pp * 2048 + col * 128 + (((kg + 0) ^ (col & 7)) << 4));
        s16x8 fr1 = *(const s16x8*)(rbuf + pp * 2048 + col * 128 + (((kg + 4) ^ (col & 7)) << 4));
        f32x4 g  = (f32x4)0.0f;
        f32x4 c2 = (f32x4)0.0f;
        g  = __builtin_amdgcn_mfma_f32_16x16x32_bf16(fr0, fr0, g, 0, 0, 0);
        g  = __builtin_amdgcn_mfma_f32_16x16x32_bf16(fr1, fr1, g, 0, 0, 0);
        c2 = __builtin_amdgcn_mfma_f32_16x16x32_bf16(ones, fr0, c2, 0, 0, 0);
        c2 = __builtin_amdgcn_mfma_f32_16x16x32_bf16(ones, fr1, c2, 0, 0, 0);
        G[c] = g;
        s[c] = c2[0] * (1.0f / 64.0f);
    }

#pragma unroll
    for (int it = 0; it < 2; ++it) {
#pragma unroll
        for (int c = 0; c < 4; ++c) {
            float sn = s[c] * s[c];
            sn = dpp_add<0xB1>(sn);          // quad xor1
            sn = dpp_add<0x4E>(sn);          // quad xor2
            sn = dpp_add<0x124>(sn);         // row_ror:4
            sn = dpp_add<0x128>(sn);         // row_ror:8
            float scale = sqrtf(sn) / (1.0f + sn);
            float v = scale * s[c];
            // 1 bpermute + 4 DPP quad-broadcasts (replaces 4 __shfl)
            int ivp = __builtin_amdgcn_ds_bpermute(pidx, __float_as_int(v));
            float v0 = __int_as_float(dpp_mov<0x00>(ivp));
            float v1 = __int_as_float(dpp_mov<0x55>(ivp));
            float v2 = __int_as_float(dpp_mov<0xAA>(ivp));
            float v3 = __int_as_float(dpp_mov<0xFF>(ivp));
            float acc = G[c][0] * v0 + G[c][1] * v1 + G[c][2] * v2 + G[c][3] * v3;
            acc += __shfl_xor(acc, 16);
            acc += __shfl_xor(acc, 32);
            s[c] += acc;
        }
    }

#pragma unroll
    for (int c = 0; c < 4; ++c) {
        float sn = s[c] * s[c];
        sn = dpp_add<0xB1>(sn);
        sn = dpp_add<0x4E>(sn);
        sn = dpp_add<0x124>(sn);
        sn = dpp_add<0x128>(sn);
        float scale = sqrtf(sn) / (1.0f + sn);
        float v = scale * s[c];
        if (l < 16)
            out[((size_t)(pos0 + c * 4 + w) * 10 + n) * 16 + col] = v;
    }
}

extern "C" void kernel_launch(void* const* d_in, const int* in_sizes, int n_in,
                              void* d_out, int out_size, void* d_ws, size_t ws_size,
                              hipStream_t stream) {
    const float* inp = (const float*)d_in[0];   // [3136][64][16]
    const float* W   = (const float*)d_in[1];   // [10][64][16][16]
    float* out = (float*)d_out;                 // [3136][10][16]

    // 10 n * 196 groups of 16 positions (196*16 = 3136); 32 KB dyn LDS
    dim3 grid(1960), block(256);
    hipLaunchKernelGGL(caps_kernel, grid, block, 32768, stream, inp, W, out);
}

// Round 14
// 30.724 us; speedup vs baseline: 1.0690x; 1.0598x over previous
//
#include <hip/hip_runtime.h>
#include <hip/hip_bf16.h>

typedef __attribute__((ext_vector_type(4))) float f32x4;
typedef __attribute__((ext_vector_type(8))) short s16x8;
typedef __attribute__((ext_vector_type(2))) __fp16 h16x2;

// inputs: [3136][64][16] f32, W: [10][64][16][16] f32, out: [3136][10][16] f32.
// Gram-space routing per (pos,n): G = R^T R (MFMA bf16), s0 = (1/64) R^T 1,
// s += G*squash(s) x2, out = squash(s).
//
// R14 = R11 (verified, 31.1us best) with ONE change: XCD-locality block
// swizzle. widx = (bid&7)*245 + (bid>>3) maps each XCD to a contiguous
// pg-major range (same-pg blocks for all 10 n adjacent on one XCD) so the
// 10x inp re-read hits that XCD's L2 (1.6MB inp + 0.64MB W < 4MB).

template<int CTRL>
__device__ __forceinline__ float dpp_add(float x) {
    int v = __builtin_amdgcn_update_dpp(0, __float_as_int(x), CTRL, 0xF, 0xF, true);
    return x + __int_as_float(v);
}
template<int CTRL>
__device__ __forceinline__ int dpp_mov(int x) {
    return __builtin_amdgcn_update_dpp(0, x, CTRL, 0xF, 0xF, true);
}
__device__ __forceinline__ h16x2 bch(int x) { return __builtin_bit_cast(h16x2, x); }
__device__ __forceinline__ int bci(h16x2 x) { return __builtin_bit_cast(int, x); }

__global__ __launch_bounds__(256, 3) void caps_kernel(
    const float* __restrict__ inp,
    const float* __restrict__ W,
    float* __restrict__ out)
{
    const int tid = threadIdx.x;
    const int w   = tid >> 6;
    const int l   = tid & 63;

    // ---- XCD-locality swizzle: 1960 = 8 XCDs x 245; widx is pg-major
    const int bid  = blockIdx.x;
    const int widx = (bid & 7) * 245 + (bid >> 3);   // 0..1959
    const int qg   = widx / 10;                      // position group 0..195
    const int n    = widx - qg * 10;                 // capsule 0..9
    const int q0   = qg * 4;                         // 4 quads = 16 positions

    extern __shared__ __align__(16) char smem[];
    char* res_s = smem;                // res double buffer: 2 x 16KB

    const int i4 = l >> 2;          // row within 16-block
    const int oq = l & 3;           // o-quad / own e-chunk
    const int i_ = w * 16 + i4;     // input capsule 0..63
    const int col = l & 15;
    const int kg  = l >> 4;

    // ---- W straight to regs, rotation-ordered, packed f16 pairs (verified)
    const float* wb = W + (size_t)n * 16384 + i_ * 256 + oq * 4;
    h16x2 wpk[32];
#pragma unroll
    for (int r = 0; r < 4; ++r) {
        int c = (oq + r) & 3;
        f32x4 w0 = *(const f32x4*)(wb + (c * 4 + 0) * 16);
        f32x4 w1 = *(const f32x4*)(wb + (c * 4 + 1) * 16);
        f32x4 w2 = *(const f32x4*)(wb + (c * 4 + 2) * 16);
        f32x4 w3 = *(const f32x4*)(wb + (c * 4 + 3) * 16);
#pragma unroll
        for (int dd = 0; dd < 4; ++dd) {
            wpk[r * 8 + dd]     = __builtin_amdgcn_cvt_pkrtz(w0[dd], w1[dd]);
            wpk[r * 8 + 4 + dd] = __builtin_amdgcn_cvt_pkrtz(w2[dd], w3[dd]);
        }
    }

    s16x8 ones;
#pragma unroll
    for (int j = 0; j < 8; ++j) ones[j] = (short)0x3F80;  // bf16 1.0

    // ---- first double-quad inp load (coalesced 16B/lane)
    f32x4 raw[8];
#pragma unroll
    for (int pp = 0; pp < 8; ++pp)
        raw[pp] = *(const f32x4*)(inp + (size_t)q0 * 4096 + pp * 1024 + w * 256 + l * 4);

#pragma unroll
    for (int t = 0; t < 2; ++t) {
        char* rbuf = res_s + (t & 1) * 16384;
        const int qb = q0 + 2 * t;          // first quad of this double-quad

        // ---- einsum (fdot2, verified): res[pp][i_][oq*4+dd] = sum_e inp*W
#pragma unroll
        for (int pp = 0; pp < 8; ++pp) {
            f32x4 a = raw[pp];
            int iA = bci(__builtin_amdgcn_cvt_pkrtz(a[0], a[1]));
            int iB = bci(__builtin_amdgcn_cvt_pkrtz(a[2], a[3]));
            float acc0 = 0.f, acc1 = 0.f, acc2 = 0.f, acc3 = 0.f;

            acc0 = __builtin_amdgcn_fdot2(bch(iA), wpk[0], acc0, false);
            acc1 = __builtin_amdgcn_fdot2(bch(iA), wpk[1], acc1, false);
            acc2 = __builtin_amdgcn_fdot2(bch(iA), wpk[2], acc2, false);
            acc3 = __builtin_amdgcn_fdot2(bch(iA), wpk[3], acc3, false);
            acc0 = __builtin_amdgcn_fdot2(bch(iB), wpk[4], acc0, false);
            acc1 = __builtin_amdgcn_fdot2(bch(iB), wpk[5], acc1, false);
            acc2 = __builtin_amdgcn_fdot2(bch(iB), wpk[6], acc2, false);
            acc3 = __builtin_amdgcn_fdot2(bch(iB), wpk[7], acc3, false);
            {
                int jA = dpp_mov<0x39>(iA), jB = dpp_mov<0x39>(iB);
                acc0 = __builtin_amdgcn_fdot2(bch(jA), wpk[8],  acc0, false);
                acc1 = __builtin_amdgcn_fdot2(bch(jA), wpk[9],  acc1, false);
                acc2 = __builtin_amdgcn_fdot2(bch(jA), wpk[10], acc2, false);
                acc3 = __builtin_amdgcn_fdot2(bch(jA), wpk[11], acc3, false);
                acc0 = __builtin_amdgcn_fdot2(bch(jB), wpk[12], acc0, false);
                acc1 = __builtin_amdgcn_fdot2(bch(jB), wpk[13], acc1, false);
                acc2 = __builtin_amdgcn_fdot2(bch(jB), wpk[14], acc2, false);
                acc3 = __builtin_amdgcn_fdot2(bch(jB), wpk[15], acc3, false);
            }
            {
                int jA = dpp_mov<0x4E>(iA), jB = dpp_mov<0x4E>(iB);
                acc0 = __builtin_amdgcn_fdot2(bch(jA), wpk[16], acc0, false);
                acc1 = __builtin_amdgcn_fdot2(bch(jA), wpk[17], acc1, false);
                acc2 = __builtin_amdgcn_fdot2(bch(jA), wpk[18], acc2, false);
                acc3 = __builtin_amdgcn_fdot2(bch(jA), wpk[19], acc3, false);
                acc0 = __builtin_amdgcn_fdot2(bch(jB), wpk[20], acc0, false);
                acc1 = __builtin_amdgcn_fdot2(bch(jB), wpk[21], acc1, false);
                acc2 = __builtin_amdgcn_fdot2(bch(jB), wpk[22], acc2, false);
                acc3 = __builtin_amdgcn_fdot2(bch(jB), wpk[23], acc3, false);
            }
            {
                int jA = dpp_mov<0x93>(iA), jB = dpp_mov<0x93>(iB);
                acc0 = __builtin_amdgcn_fdot2(bch(jA), wpk[24], acc0, false);
                acc1 = __builtin_amdgcn_fdot2(bch(jA), wpk[25], acc1, false);
                acc2 = __builtin_amdgcn_fdot2(bch(jA), wpk[26], acc2, false);
                acc3 = __builtin_amdgcn_fdot2(bch(jA), wpk[27], acc3, false);
                acc0 = __builtin_amdgcn_fdot2(bch(jB), wpk[28], acc0, false);
                acc1 = __builtin_amdgcn_fdot2(bch(jB), wpk[29], acc1, false);
                acc2 = __builtin_amdgcn_fdot2(bch(jB), wpk[30], acc2, false);
                acc3 = __builtin_amdgcn_fdot2(bch(jB), wpk[31], acc3, false);
            }

            float accv[4] = {acc0, acc1, acc2, acc3};
#pragma unroll
            for (int dd = 0; dd < 4; ++dd) {
                int o = oq * 4 + dd;
                __hip_bfloat16 bb = __float2bfloat16(accv[dd]);
                int byte = pp * 2048 + o * 128 + (((i_ >> 3) ^ (o & 7)) << 4) + (i_ & 7) * 2;
                *(unsigned short*)(rbuf + byte) = *(unsigned short*)&bb;
            }
        }

        // issue next double-quad loads now; they complete under phase B
        if (t == 0) {
#pragma unroll
            for (int pp = 0; pp < 8; ++pp)
                raw[pp] = *(const f32x4*)(inp + (size_t)(q0 + 2) * 4096 + pp * 1024 + w * 256 + l * 4);
        }

        // one barrier per double-quad (res double-buffered)
        asm volatile("s_waitcnt lgkmcnt(0)" ::: "memory");
        __builtin_amdgcn_s_barrier();
        asm volatile("" ::: "memory");
        __builtin_amdgcn_sched_barrier(0);

        // ---- phase B (verified): wave w handles pp = w and pp = w+4
        float s[2];
        f32x4 G[2];
#pragma unroll
        for (int c = 0; c < 2; ++c) {
            const int pp = w + 4 * c;
            s16x8 fr0 = *(const s16x8*)(rbuf + pp * 2048 + col * 128 + (((kg + 0) ^ (col & 7)) << 4));
            s16x8 fr1 = *(const s16x8*)(rbuf + pp * 2048 + col * 128 + (((kg + 4) ^ (col & 7)) << 4));
            f32x4 g  = (f32x4)0.0f;
            f32x4 c2 = (f32x4)0.0f;
            g  = __builtin_amdgcn_mfma_f32_16x16x32_bf16(fr0, fr0, g, 0, 0, 0);
            g  = __builtin_amdgcn_mfma_f32_16x16x32_bf16(fr1, fr1, g, 0, 0, 0);
            c2 = __builtin_amdgcn_mfma_f32_16x16x32_bf16(ones, fr0, c2, 0, 0, 0);
            c2 = __builtin_amdgcn_mfma_f32_16x16x32_bf16(ones, fr1, c2, 0, 0, 0);
            G[c] = g;
            s[c] = c2[0] * (1.0f / 64.0f);
        }

#pragma unroll
        for (int it = 0; it < 2; ++it) {
#pragma unroll
            for (int c = 0; c < 2; ++c) {
                float sn = s[c] * s[c];
                sn = dpp_add<0xB1>(sn);
                sn = dpp_add<0x4E>(sn);
                sn = dpp_add<0x124>(sn);
                sn = dpp_add<0x128>(sn);
                float scale = sqrtf(sn) / (1.0f + sn);
                float v = scale * s[c];
                float v0 = __shfl(v, kg * 4 + 0);
                float v1 = __shfl(v, kg * 4 + 1);
                float v2 = __shfl(v, kg * 4 + 2);
                float v3 = __shfl(v, kg * 4 + 3);
                float acc = G[c][0] * v0 + G[c][1] * v1 + G[c][2] * v2 + G[c][3] * v3;
                acc += __shfl_xor(acc, 16);
                acc += __shfl_xor(acc, 32);
                s[c] += acc;
            }
        }

#pragma unroll
        for (int c = 0; c < 2; ++c) {
            float sn = s[c] * s[c];
            sn = dpp_add<0xB1>(sn);
            sn = dpp_add<0x4E>(sn);
            sn = dpp_add<0x124>(sn);
            sn = dpp_add<0x128>(sn);
            float scale = sqrtf(sn) / (1.0f + sn);
            float v = scale * s[c];
            if (l < 16)
                out[((size_t)((qb + c) * 4 + w) * 10 + n) * 16 + col] = v;
        }
    }
}

extern "C" void kernel_launch(void* const* d_in, const int* in_sizes, int n_in,
                              void* d_out, int out_size, void* d_ws, size_t ws_size,
                              hipStream_t stream) {
    const float* inp = (const float*)d_in[0];   // [3136][64][16]
    const float* W   = (const float*)d_in[1];   // [10][64][16][16]
    float* out = (float*)d_out;                 // [3136][10][16]

    // 10 n * 196 groups of 4 quads; XCD swizzle inside kernel; 32 KB dyn LDS
    dim3 grid(1960), block(256);
    hipLaunchKernelGGL(caps_kernel, grid, block, 32768, stream, inp, W, out);
}